// Round 1
// baseline (894.113 us; speedup 1.0000x reference)
//
#include <hip/hip_runtime.h>
#include <math.h>

#define KK   128
#define HH   512
#define TOPK 8

// One block per row n. 256 threads = 4 waves.
// Wave w computes sims for k in [w*32, w*32+32); wave 0 then does top-8 +
// softmax; whole block does the weighted gather from mem_v.
__global__ __launch_bounds__(256) void lm_kernel(
    const float* __restrict__ q,
    const float* __restrict__ mem_k,
    const float* __restrict__ mem_v,
    const float* __restrict__ mem_m,
    float* __restrict__ out)
{
    const int n    = blockIdx.x;
    const int tid  = threadIdx.x;
    const int wave = tid >> 6;
    const int lane = tid & 63;

    __shared__ float s_sim[KK];
    __shared__ float s_attn[TOPK];
    __shared__ int   s_idx[TOPK];

    // --- q chunk in registers: lane l holds q[8l .. 8l+7] ---
    const float4* qv = (const float4*)(q + (size_t)n * HH) + lane * 2;
    const float4 qa = qv[0];
    const float4 qb = qv[1];

    float qss = qa.x*qa.x + qa.y*qa.y + qa.z*qa.z + qa.w*qa.w
              + qb.x*qb.x + qb.y*qb.y + qb.z*qb.z + qb.w*qb.w;
    #pragma unroll
    for (int m = 1; m < 64; m <<= 1) qss += __shfl_xor(qss, m, 64);
    const float qn = fmaxf(sqrtf(qss), 1e-12f);

    // --- cosine sims (masked) ---
    const float* kbase = mem_k + (size_t)n * KK * HH;
    const float* mrow  = mem_m + (size_t)n * KK;
    const int k0 = wave * 32;
    for (int k = k0; k < k0 + 32; ++k) {
        const float4* kv = (const float4*)(kbase + (size_t)k * HH) + lane * 2;
        const float4 ka = kv[0];
        const float4 kb = kv[1];
        float dot = qa.x*ka.x + qa.y*ka.y + qa.z*ka.z + qa.w*ka.w
                  + qb.x*kb.x + qb.y*kb.y + qb.z*kb.z + qb.w*kb.w;
        float kss = ka.x*ka.x + ka.y*ka.y + ka.z*ka.z + ka.w*ka.w
                  + kb.x*kb.x + kb.y*kb.y + kb.z*kb.z + kb.w*kb.w;
        #pragma unroll
        for (int m = 1; m < 64; m <<= 1) {
            dot += __shfl_xor(dot, m, 64);
            kss += __shfl_xor(kss, m, 64);
        }
        if (lane == 0) {
            const float kn  = fmaxf(sqrtf(kss), 1e-12f);
            float sim = dot / (qn * kn);
            if (mrow[k] <= 0.0f) sim = -1e9f;
            s_sim[k] = sim;
        }
    }
    __syncthreads();

    // --- top-8 (lowest-index tie-break, matching jax.lax.top_k) + softmax ---
    if (wave == 0) {
        float va = s_sim[lane];
        float vb = s_sim[lane + 64];
        float topv[TOPK];
        int   topi[TOPK];
        #pragma unroll
        for (int j = 0; j < TOPK; ++j) {
            float bv; int bi;
            if (vb > va) { bv = vb; bi = lane + 64; }
            else         { bv = va; bi = lane; }
            #pragma unroll
            for (int m = 1; m < 64; m <<= 1) {
                const float ov = __shfl_xor(bv, m, 64);
                const int   oi = __shfl_xor(bi, m, 64);
                if (ov > bv || (ov == bv && oi < bi)) { bv = ov; bi = oi; }
            }
            topv[j] = bv; topi[j] = bi;
            if (bi == lane)      va = -INFINITY;
            if (bi == lane + 64) vb = -INFINITY;
        }
        // softmax over topv; topv[0] is the max (descending selection order)
        float e[TOPK];
        float ssum = 0.0f;
        #pragma unroll
        for (int j = 0; j < TOPK; ++j) { e[j] = expf(topv[j] - topv[0]); ssum += e[j]; }
        if (lane == 0) {
            const float inv = 1.0f / ssum;
            #pragma unroll
            for (int j = 0; j < TOPK; ++j) { s_attn[j] = e[j] * inv; s_idx[j] = topi[j]; }
        }
    }
    __syncthreads();

    // --- weighted gather: out[n] = sum_j attn[j] * mem_v[n, idx[j], :] ---
    const float* vbase = mem_v + (size_t)n * KK * HH;
    const int h = tid * 2;            // 512 outputs / 256 threads = 2 each
    float acc0 = 0.0f, acc1 = 0.0f;
    #pragma unroll
    for (int j = 0; j < TOPK; ++j) {
        const float  a  = s_attn[j];
        const float2 vv = *(const float2*)(vbase + (size_t)s_idx[j] * HH + h);
        acc0 += a * vv.x;
        acc1 += a * vv.y;
    }
    float2 o; o.x = acc0; o.y = acc1;
    *(float2*)(out + (size_t)n * HH + h) = o;
}

extern "C" void kernel_launch(void* const* d_in, const int* in_sizes, int n_in,
                              void* d_out, int out_size, void* d_ws, size_t ws_size,
                              hipStream_t stream) {
    const float* q     = (const float*)d_in[0];
    const float* mem_k = (const float*)d_in[1];
    const float* mem_v = (const float*)d_in[2];
    const float* mem_m = (const float*)d_in[3];
    float* out = (float*)d_out;
    const int n_rows = in_sizes[0] / HH;   // 2048
    lm_kernel<<<n_rows, 256, 0, stream>>>(q, mem_k, mem_v, mem_m, out);
}

// Round 2
// 890.960 us; speedup vs baseline: 1.0035x; 1.0035x over previous
//
#include <hip/hip_runtime.h>
#include <math.h>

#define KK   128
#define HH   512
#define TOPK 8

// One block per row n. 256 threads = 4 waves.
// Wave w owns k-rows [w*32, w*32+32). Within a wave, 4 groups of 16 lanes
// each compute one row's dot/sumsq per iteration (4 rows per iteration,
// 8 iterations), with a register double-buffer so the next iteration's
// 8 float4 loads are in flight during the current reduce.
__global__ __launch_bounds__(256) void lm_kernel(
    const float* __restrict__ q,
    const float* __restrict__ mem_k,
    const float* __restrict__ mem_v,
    const float* __restrict__ mem_m,
    float* __restrict__ out)
{
    const int n    = blockIdx.x;
    const int tid  = threadIdx.x;
    const int wave = tid >> 6;
    const int lane = tid & 63;
    const int g    = lane >> 4;   // dot-group 0..3 within wave
    const int s    = lane & 15;   // lane within group

    __shared__ float s_sim[KK];
    __shared__ float s_attn[TOPK];
    __shared__ int   s_idx[TOPK];

    // --- q fragment: lane covers h = s*4 + j*64, j=0..7 (32 floats) ---
    const float* qrow = q + (size_t)n * HH;
    float4 qv[8];
    #pragma unroll
    for (int j = 0; j < 8; ++j)
        qv[j] = *(const float4*)(qrow + j * 64 + s * 4);

    float qss = 0.0f;
    #pragma unroll
    for (int j = 0; j < 8; ++j)
        qss += qv[j].x*qv[j].x + qv[j].y*qv[j].y + qv[j].z*qv[j].z + qv[j].w*qv[j].w;
    #pragma unroll
    for (int m = 1; m < 16; m <<= 1) qss += __shfl_xor(qss, m, 16);
    const float qn = fmaxf(sqrtf(qss), 1e-12f);

    // --- cosine sims: 4 rows/iter/wave, register double-buffered ---
    const float* kbase = mem_k + (size_t)n * KK * HH;
    const float* mrow  = mem_m + (size_t)n * KK;
    const int k0 = wave * 32;

    float4 bufA[8], bufB[8];
    {
        const float* p = kbase + (size_t)(k0 + g) * HH + s * 4;
        #pragma unroll
        for (int j = 0; j < 8; ++j) bufA[j] = *(const float4*)(p + j * 64);
    }

    #pragma unroll
    for (int i = 0; i < 8; ++i) {
        const float4* cur = (i & 1) ? bufB : bufA;   // compile-time after unroll
        float4*       nxt = (i & 1) ? bufA : bufB;
        if (i < 7) {
            const float* p = kbase + (size_t)(k0 + (i + 1) * 4 + g) * HH + s * 4;
            #pragma unroll
            for (int j = 0; j < 8; ++j) nxt[j] = *(const float4*)(p + j * 64);
        }
        float d0 = 0.0f, d1 = 0.0f, ks0 = 0.0f, ks1 = 0.0f;
        #pragma unroll
        for (int j = 0; j < 8; j += 2) {
            d0  += qv[j].x*cur[j].x + qv[j].y*cur[j].y + qv[j].z*cur[j].z + qv[j].w*cur[j].w;
            ks0 += cur[j].x*cur[j].x + cur[j].y*cur[j].y + cur[j].z*cur[j].z + cur[j].w*cur[j].w;
            d1  += qv[j+1].x*cur[j+1].x + qv[j+1].y*cur[j+1].y + qv[j+1].z*cur[j+1].z + qv[j+1].w*cur[j+1].w;
            ks1 += cur[j+1].x*cur[j+1].x + cur[j+1].y*cur[j+1].y + cur[j+1].z*cur[j+1].z + cur[j+1].w*cur[j+1].w;
        }
        float dot = d0 + d1;
        float kss = ks0 + ks1;
        #pragma unroll
        for (int m = 1; m < 16; m <<= 1) {
            dot += __shfl_xor(dot, m, 16);
            kss += __shfl_xor(kss, m, 16);
        }
        if (s == 0) {
            const int k = k0 + i * 4 + g;
            float sim = dot / (qn * fmaxf(sqrtf(kss), 1e-12f));
            if (mrow[k] <= 0.0f) sim = -1e9f;
            s_sim[k] = sim;
        }
    }
    __syncthreads();

    // --- top-8 (lowest-index tie-break, matches jax.lax.top_k) + softmax ---
    if (wave == 0) {
        float va = s_sim[lane];
        float vb = s_sim[lane + 64];
        float topv[TOPK];
        int   topi[TOPK];
        #pragma unroll
        for (int j = 0; j < TOPK; ++j) {
            float bv; int bi;
            if (vb > va) { bv = vb; bi = lane + 64; }
            else         { bv = va; bi = lane; }
            #pragma unroll
            for (int m = 1; m < 64; m <<= 1) {
                const float ov = __shfl_xor(bv, m, 64);
                const int   oi = __shfl_xor(bi, m, 64);
                if (ov > bv || (ov == bv && oi < bi)) { bv = ov; bi = oi; }
            }
            topv[j] = bv; topi[j] = bi;
            if (bi == lane)      va = -INFINITY;
            if (bi == lane + 64) vb = -INFINITY;
        }
        float e[TOPK];
        float ssum = 0.0f;
        #pragma unroll
        for (int j = 0; j < TOPK; ++j) { e[j] = expf(topv[j] - topv[0]); ssum += e[j]; }
        if (lane == 0) {
            const float inv = 1.0f / ssum;
            #pragma unroll
            for (int j = 0; j < TOPK; ++j) { s_attn[j] = e[j] * inv; s_idx[j] = topi[j]; }
        }
    }
    __syncthreads();

    // --- weighted gather: out[n] = sum_j attn[j] * mem_v[n, idx[j], :] ---
    const float* vbase = mem_v + (size_t)n * KK * HH;
    const int h = tid * 2;            // 512 outputs / 256 threads
    float acc0 = 0.0f, acc1 = 0.0f;
    #pragma unroll
    for (int j = 0; j < TOPK; ++j) {
        const float  a  = s_attn[j];
        const float2 vv = *(const float2*)(vbase + (size_t)s_idx[j] * HH + h);
        acc0 += a * vv.x;
        acc1 += a * vv.y;
    }
    float2 o; o.x = acc0; o.y = acc1;
    *(float2*)(out + (size_t)n * HH + h) = o;
}

extern "C" void kernel_launch(void* const* d_in, const int* in_sizes, int n_in,
                              void* d_out, int out_size, void* d_ws, size_t ws_size,
                              hipStream_t stream) {
    const float* q     = (const float*)d_in[0];
    const float* mem_k = (const float*)d_in[1];
    const float* mem_v = (const float*)d_in[2];
    const float* mem_m = (const float*)d_in[3];
    float* out = (float*)d_out;
    const int n_rows = in_sizes[0] / HH;   // 2048
    lm_kernel<<<n_rows, 256, 0, stream>>>(q, mem_k, mem_v, mem_m, out);
}